// Round 1
// baseline (687.587 us; speedup 1.0000x reference)
//
#include <hip/hip_runtime.h>
#include <math.h>

#define N_MEL 80
#define B_    64
#define T_    2000
#define L_    200
#define ROWS   (B_*N_MEL)        // 5120
#define NTOT   (B_*N_MEL*T_)     // 10,240,000
#define GATE_N (B_*T_)           // 128,000
#define ATT_ROWS (B_*T_)         // 128,000

// ws layout (float indices)
#define WS_M     16               // gram partial M[b*6400 + c*80 + d], 409600 floats
#define WS_PEAKS (16 + 409600)    // 128000 floats
// accumulators (ws[0..15]):
// 0: sum(mo-mt)^2   1: sum(mp-mt)^2   2: sum w2[c]*(d)^2   3: sum|d|
// 4: sum(d_t-d_{t-1})^2   5: sum fw[c]*d^2   6: sum(meandiff^2)  7: sum(vardiff^2)
// 8: gate BCE sum   9: viol sum   10: gram sq sum

__device__ __forceinline__ float blockReduceSum256(float v) {
    __shared__ float red[4];
    #pragma unroll
    for (int off = 32; off; off >>= 1) v += __shfl_down(v, off, 64);
    int lane = threadIdx.x & 63, w = threadIdx.x >> 6;
    if (lane == 0) red[w] = v;
    __syncthreads();
    if (threadIdx.x == 0) v = red[0] + red[1] + red[2] + red[3];
    return v;  // valid on thread 0 only
}

// ---------------- Kernel 1: per-(b,c) row pass over mel tensors ----------------
__global__ __launch_bounds__(256) void k_melrow(const float* __restrict__ mo,
                                                const float* __restrict__ mp,
                                                const float* __restrict__ mt,
                                                float* __restrict__ acc) {
    const int row = blockIdx.x;            // b*80 + c
    const int c = row % N_MEL;
    const long base = (long)row * T_;
    const float4* mo4 = (const float4*)(mo + base);
    const float4* mp4 = (const float4*)(mp + base);
    const float4* mt4 = (const float4*)(mt + base);

    float s1 = 0, s2 = 0, sl1 = 0, std_ = 0, sp = 0, sp2 = 0, st = 0, st2 = 0;
    for (int i = threadIdx.x; i < T_/4; i += 256) {
        float4 a = mo4[i], p = mp4[i], t = mt4[i];
        float e0 = a.x - t.x, e1 = a.y - t.y, e2 = a.z - t.z, e3 = a.w - t.w;
        s1 += e0*e0 + e1*e1 + e2*e2 + e3*e3;
        float d0 = p.x - t.x, d1 = p.y - t.y, d2 = p.z - t.z, d3 = p.w - t.w;
        s2 += d0*d0 + d1*d1 + d2*d2 + d3*d3;
        sl1 += fabsf(d0) + fabsf(d1) + fabsf(d2) + fabsf(d3);
        sp  += p.x + p.y + p.z + p.w;
        sp2 += p.x*p.x + p.y*p.y + p.z*p.z + p.w*p.w;
        st  += t.x + t.y + t.z + t.w;
        st2 += t.x*t.x + t.y*t.y + t.z*t.z + t.w*t.w;
        float q1 = d1 - d0, q2 = d2 - d1, q3 = d3 - d2;
        std_ += q1*q1 + q2*q2 + q3*q3;
        if (i > 0) {
            float dprev = mp[base + 4*i - 1] - mt[base + 4*i - 1];
            float q0 = d0 - dprev;
            std_ += q0*q0;
        }
    }

    __shared__ float red[4][8];
    float vals[8] = {s1, s2, sl1, std_, sp, sp2, st, st2};
    #pragma unroll
    for (int k = 0; k < 8; k++) {
        float v = vals[k];
        #pragma unroll
        for (int off = 32; off; off >>= 1) v += __shfl_down(v, off, 64);
        vals[k] = v;
    }
    int lane = threadIdx.x & 63, w = threadIdx.x >> 6;
    if (lane == 0) {
        #pragma unroll
        for (int k = 0; k < 8; k++) red[w][k] = vals[k];
    }
    __syncthreads();
    if (threadIdx.x == 0) {
        float r[8];
        #pragma unroll
        for (int k = 0; k < 8; k++) r[k] = red[0][k] + red[1][k] + red[2][k] + red[3][k];
        float wc = (c >= 3*N_MEL/4) ? 0.8f : ((c >= N_MEL/4) ? 1.5f : 1.0f);
        float fw = expf(-(float)c / 20.0f);
        atomicAdd(&acc[0], r[0]);
        atomicAdd(&acc[1], r[1]);
        atomicAdd(&acc[2], wc*wc*r[1]);
        atomicAdd(&acc[3], r[2]);
        atomicAdd(&acc[4], r[3]);
        atomicAdd(&acc[5], fw*r[1]);
        float md = (r[4] - r[6]) * (1.0f / T_);
        atomicAdd(&acc[6], md*md);
        float vp = (r[5] - r[4]*r[4]*(1.0f/T_)) * (1.0f/(T_-1));
        float vt = (r[7] - r[6]*r[6]*(1.0f/T_)) * (1.0f/(T_-1));
        float vd = vp - vt;
        atomicAdd(&acc[7], vd*vd);
    }
}

// ---------------- Kernel 2: gate BCE-with-logits ----------------
__global__ __launch_bounds__(256) void k_gate(const float* __restrict__ xp,
                                              const float* __restrict__ tp,
                                              float* __restrict__ acc) {
    const float4* x4 = (const float4*)xp;
    const float4* t4 = (const float4*)tp;
    float s = 0;
    for (int i = blockIdx.x*256 + threadIdx.x; i < GATE_N/4; i += gridDim.x*256) {
        float4 x = x4[i], t = t4[i];
        float xs[4] = {x.x, x.y, x.z, x.w}, ts[4] = {t.x, t.y, t.z, t.w};
        #pragma unroll
        for (int k = 0; k < 4; k++)
            s += fmaxf(xs[k], 0.0f) - xs[k]*ts[k] + log1pf(expf(-fabsf(xs[k])));
    }
    float tot = blockReduceSum256(s);
    if (threadIdx.x == 0) atomicAdd(&acc[8], tot);
}

// ---------------- Kernel 3a: per-(b,t) argmax over L=200 (first-index ties) ----------------
__global__ __launch_bounds__(256) void k_argmax(const float* __restrict__ att,
                                                float* __restrict__ peaks) {
    int gwid = (blockIdx.x*256 + threadIdx.x) >> 6;
    int lane = threadIdx.x & 63;
    int nw = (gridDim.x*256) >> 6;
    for (int r = gwid; r < ATT_ROWS; r += nw) {
        const float* rowp = att + (long)r * L_;
        unsigned long long best = 0;
        #pragma unroll
        for (int k = 0; k < 4; k++) {
            int idx = lane + 64*k;
            if (idx < L_) {
                float v = rowp[idx];  // uniform [0,1): positive, int-monotonic bits
                unsigned long long key =
                    ((unsigned long long)__float_as_uint(v) << 32) | (unsigned)(L_-1-idx);
                best = key > best ? key : best;
            }
        }
        #pragma unroll
        for (int off = 32; off; off >>= 1) {
            unsigned long long o = __shfl_down(best, off, 64);
            best = o > best ? o : best;
        }
        if (lane == 0) peaks[r] = (float)(L_ - 1 - (int)(best & 0xffffffffu));
    }
}

// ---------------- Kernel 3b: monotonic violations ----------------
__global__ __launch_bounds__(256) void k_viol(const float* __restrict__ peaks,
                                              float* __restrict__ acc) {
    int i = blockIdx.x*256 + threadIdx.x;  // grid sized exactly ATT_ROWS
    float v = 0;
    if (((i + 1) % T_) != 0)
        v = fmaxf(peaks[i] - peaks[i+1], 0.0f);
    float tot = blockReduceSum256(v);
    if (threadIdx.x == 0) atomicAdd(&acc[9], tot);
}

// ---------------- Kernel 4: Gram partial M = D * S^T (per batch, K-chunked) ----------------
#define GTK  20
#define GPAD 28
__global__ __launch_bounds__(256) void k_gram(const float* __restrict__ mp,
                                              const float* __restrict__ mt,
                                              float* __restrict__ M) {
    const int b  = blockIdx.x >> 2;
    const int ch = blockIdx.x & 3;
    const int k0 = ch * 500;
    __shared__ float Dt[N_MEL][GPAD];
    __shared__ float St[N_MEL][GPAD];
    const int tx = threadIdx.x & 15, ty = threadIdx.x >> 4;
    float m[5][5];
    #pragma unroll
    for (int i = 0; i < 5; i++)
        #pragma unroll
        for (int j = 0; j < 5; j++) m[i][j] = 0;

    const long bbase = (long)b * (N_MEL * T_);
    for (int kt = 0; kt < 25; kt++) {
        int kb = k0 + kt*GTK;
        for (int idx = threadIdx.x; idx < N_MEL*(GTK/4); idx += 256) {
            int c = idx / (GTK/4), q = idx % (GTK/4);
            const float4 p = *(const float4*)(mp + bbase + (long)c*T_ + kb + q*4);
            const float4 t = *(const float4*)(mt + bbase + (long)c*T_ + kb + q*4);
            *(float4*)&Dt[c][q*4] = make_float4(p.x-t.x, p.y-t.y, p.z-t.z, p.w-t.w);
            *(float4*)&St[c][q*4] = make_float4(p.x+t.x, p.y+t.y, p.z+t.z, p.w+t.w);
        }
        __syncthreads();
        #pragma unroll
        for (int q = 0; q < GTK/4; q++) {
            float4 a[5], bb[5];
            #pragma unroll
            for (int i = 0; i < 5; i++) a[i]  = *(const float4*)&Dt[tx + 16*i][q*4];
            #pragma unroll
            for (int j = 0; j < 5; j++) bb[j] = *(const float4*)&St[ty + 16*j][q*4];
            #pragma unroll
            for (int i = 0; i < 5; i++)
                #pragma unroll
                for (int j = 0; j < 5; j++)
                    m[i][j] += a[i].x*bb[j].x + a[i].y*bb[j].y
                             + a[i].z*bb[j].z + a[i].w*bb[j].w;
        }
        __syncthreads();
    }
    #pragma unroll
    for (int i = 0; i < 5; i++)
        #pragma unroll
        for (int j = 0; j < 5; j++)
            atomicAdd(&M[b*6400 + (tx + 16*i)*80 + (ty + 16*j)], m[i][j]);
}

// ---------------- Kernel 5: gram finalize: sum ((M + M^T)/2 / (C*T))^2 ----------------
__global__ __launch_bounds__(256) void k_gramfin(const float* __restrict__ M,
                                                 float* __restrict__ acc) {
    const float inv = 1.0f / (float)(N_MEL * T_);
    float s = 0;
    for (int i = blockIdx.x*256 + threadIdx.x; i < B_*6400; i += gridDim.x*256) {
        int b = i / 6400, cd = i % 6400, c = cd / 80, d = cd % 80;
        float g = 0.5f * (M[i] + M[b*6400 + d*80 + c]) * inv;
        s += g * g;
    }
    float tot = blockReduceSum256(s);
    if (threadIdx.x == 0) atomicAdd(&acc[10], tot);
}

// ---------------- Kernel 6: combine ----------------
__global__ void k_final(const float* __restrict__ acc, float* __restrict__ out) {
    if (threadIdx.x == 0 && blockIdx.x == 0) {
        const float invN = 1.0f / (float)NTOT;
        float mel        = (acc[0] + acc[1]) * invN;
        float gate       = 1.3f * acc[8] / (float)GATE_N;
        float wmse       = acc[2] * invN;
        float l1         = acc[3] * invN;
        float sdiff      = acc[4] / (float)(B_ * N_MEL * (T_ - 1));
        float spectral   = wmse + 0.3f*l1 + 0.2f*sdiff;
        float perceptual = acc[5]*invN + 0.5f*l1;
        float mean_loss  = acc[6] / (float)ROWS;
        float var_loss   = acc[7] / (float)ROWS;
        float gram       = acc[10] / (float)(B_ * 6400);
        float style      = mean_loss + var_loss + 0.5f*gram;
        float mono       = acc[9] / (float)(B_ * T_);
        out[0] = mel + gate + 0.3f*spectral + 0.2f*perceptual + 0.1f*style + 0.1f*mono;
    }
}

extern "C" void kernel_launch(void* const* d_in, const int* in_sizes, int n_in,
                              void* d_out, int out_size, void* d_ws, size_t ws_size,
                              hipStream_t stream) {
    const float* mo  = (const float*)d_in[0];
    const float* mp  = (const float*)d_in[1];
    const float* mt  = (const float*)d_in[2];
    const float* gx  = (const float*)d_in[3];
    const float* gt  = (const float*)d_in[4];
    const float* att = (const float*)d_in[5];
    float* ws    = (float*)d_ws;
    float* acc   = ws;
    float* M     = ws + WS_M;
    float* peaks = ws + WS_PEAKS;

    // zero accumulators + gram partial buffer (acc..M end); peaks fully overwritten
    hipMemsetAsync(d_ws, 0, (size_t)(WS_M + 409600) * sizeof(float), stream);

    k_melrow <<<ROWS, 256, 0, stream>>>(mo, mp, mt, acc);
    k_gate   <<<64,   256, 0, stream>>>(gx, gt, acc);
    k_argmax <<<500,  256, 0, stream>>>(att, peaks);
    k_viol   <<<500,  256, 0, stream>>>(peaks, acc);
    k_gram   <<<256,  256, 0, stream>>>(mp, mt, M);
    k_gramfin<<<512,  256, 0, stream>>>(M, acc);
    k_final  <<<1,    64,  0, stream>>>(acc, (float*)d_out);
}

// Round 2
// 175.881 us; speedup vs baseline: 3.9094x; 3.9094x over previous
//
#include <hip/hip_runtime.h>
#include <math.h>

#define N_MEL 80
#define B_    64
#define T_    2000
#define L_    200
#define ROWS   (B_*N_MEL)        // 5120
#define NTOT   (B_*N_MEL*T_)     // 10,240,000
#define GATE_N (B_*T_)           // 128,000
#define ATT_ROWS (B_*T_)         // 128,000

// ws layout (float indices). Accumulators are spaced 16 floats (64 B) apart
// to avoid same-cache-line atomic serialization.
#define ACC_STRIDE 16
#define WS_M       256                    // gram partial M[b*6400 + c*80 + d], 409600 floats
#define WS_PEAKS   (WS_M + 409600)        // 128000 floats
#define WS_ROWPART (WS_PEAKS + 128000)    // 5120*8 floats
// accumulator slots (k -> ws[k*16]):
// 0: sum(mo-mt)^2   1: sum(mp-mt)^2   2: sum w2[c]*d^2   3: sum|d|
// 4: sum(d_t-d_{t-1})^2   5: sum fw[c]*d^2   6: sum(meandiff^2)  7: sum(vardiff^2)
// 8: gate BCE sum   9: viol sum   10: gram sq sum

__device__ __forceinline__ float blockReduceSum256(float v) {
    __shared__ float red[4];
    #pragma unroll
    for (int off = 32; off; off >>= 1) v += __shfl_down(v, off, 64);
    int lane = threadIdx.x & 63, w = threadIdx.x >> 6;
    if (lane == 0) red[w] = v;
    __syncthreads();
    if (threadIdx.x == 0) v = red[0] + red[1] + red[2] + red[3];
    return v;  // valid on thread 0 only
}

// ---------------- Kernel 1: per-(b,c) row pass over mel tensors ----------------
__global__ __launch_bounds__(256) void k_melrow(const float* __restrict__ mo,
                                                const float* __restrict__ mp,
                                                const float* __restrict__ mt,
                                                float* __restrict__ rowpart) {
    const int row = blockIdx.x;            // b*80 + c
    const long base = (long)row * T_;
    const float4* mo4 = (const float4*)(mo + base);
    const float4* mp4 = (const float4*)(mp + base);
    const float4* mt4 = (const float4*)(mt + base);

    float s1 = 0, s2 = 0, sl1 = 0, std_ = 0, sp = 0, sp2 = 0, st = 0, st2 = 0;
    for (int i = threadIdx.x; i < T_/4; i += 256) {
        float4 a = mo4[i], p = mp4[i], t = mt4[i];
        float e0 = a.x - t.x, e1 = a.y - t.y, e2 = a.z - t.z, e3 = a.w - t.w;
        s1 += e0*e0 + e1*e1 + e2*e2 + e3*e3;
        float d0 = p.x - t.x, d1 = p.y - t.y, d2 = p.z - t.z, d3 = p.w - t.w;
        s2 += d0*d0 + d1*d1 + d2*d2 + d3*d3;
        sl1 += fabsf(d0) + fabsf(d1) + fabsf(d2) + fabsf(d3);
        sp  += p.x + p.y + p.z + p.w;
        sp2 += p.x*p.x + p.y*p.y + p.z*p.z + p.w*p.w;
        st  += t.x + t.y + t.z + t.w;
        st2 += t.x*t.x + t.y*t.y + t.z*t.z + t.w*t.w;
        float q1 = d1 - d0, q2 = d2 - d1, q3 = d3 - d2;
        std_ += q1*q1 + q2*q2 + q3*q3;
        if (i > 0) {
            float dprev = mp[base + 4*i - 1] - mt[base + 4*i - 1];
            float q0 = d0 - dprev;
            std_ += q0*q0;
        }
    }

    __shared__ float red[4][8];
    float vals[8] = {s1, s2, sl1, std_, sp, sp2, st, st2};
    #pragma unroll
    for (int k = 0; k < 8; k++) {
        float v = vals[k];
        #pragma unroll
        for (int off = 32; off; off >>= 1) v += __shfl_down(v, off, 64);
        vals[k] = v;
    }
    int lane = threadIdx.x & 63, w = threadIdx.x >> 6;
    if (lane == 0) {
        #pragma unroll
        for (int k = 0; k < 8; k++) red[w][k] = vals[k];
    }
    __syncthreads();
    if (threadIdx.x == 0) {
        #pragma unroll
        for (int k = 0; k < 8; k++)
            rowpart[row*8 + k] = red[0][k] + red[1][k] + red[2][k] + red[3][k];
    }
}

// ---------------- Kernel 1b: reduce per-row partials with channel weights ----------------
__global__ __launch_bounds__(256) void k_melred(const float* __restrict__ rowpart,
                                                float* __restrict__ acc) {
    int row = blockIdx.x*256 + threadIdx.x;
    float a[8] = {0,0,0,0,0,0,0,0};
    if (row < ROWS) {
        const float4 lo = *(const float4*)(rowpart + row*8);
        const float4 hi = *(const float4*)(rowpart + row*8 + 4);
        float r0=lo.x, r1=lo.y, r2=lo.z, r3=lo.w, r4=hi.x, r5=hi.y, r6=hi.z, r7=hi.w;
        int c = row % N_MEL;
        float wc = (c >= 3*N_MEL/4) ? 0.8f : ((c >= N_MEL/4) ? 1.5f : 1.0f);
        float fw = expf(-(float)c / 20.0f);
        a[0] = r0;
        a[1] = r1;
        a[2] = wc*wc*r1;
        a[3] = r2;
        a[4] = r3;
        a[5] = fw*r1;
        float md = (r4 - r6) * (1.0f / T_);
        a[6] = md*md;
        float vp = (r5 - r4*r4*(1.0f/T_)) * (1.0f/(T_-1));
        float vt = (r7 - r6*r6*(1.0f/T_)) * (1.0f/(T_-1));
        float vd = vp - vt;
        a[7] = vd*vd;
    }
    __shared__ float red[4][8];
    #pragma unroll
    for (int k = 0; k < 8; k++) {
        float v = a[k];
        #pragma unroll
        for (int off = 32; off; off >>= 1) v += __shfl_down(v, off, 64);
        a[k] = v;
    }
    int lane = threadIdx.x & 63, w = threadIdx.x >> 6;
    if (lane == 0) {
        #pragma unroll
        for (int k = 0; k < 8; k++) red[w][k] = a[k];
    }
    __syncthreads();
    if (threadIdx.x == 0) {
        #pragma unroll
        for (int k = 0; k < 8; k++)
            atomicAdd(&acc[k*ACC_STRIDE], red[0][k] + red[1][k] + red[2][k] + red[3][k]);
    }
}

// ---------------- Kernel 2: gate BCE-with-logits ----------------
__global__ __launch_bounds__(256) void k_gate(const float* __restrict__ xp,
                                              const float* __restrict__ tp,
                                              float* __restrict__ acc) {
    const float4* x4 = (const float4*)xp;
    const float4* t4 = (const float4*)tp;
    float s = 0;
    for (int i = blockIdx.x*256 + threadIdx.x; i < GATE_N/4; i += gridDim.x*256) {
        float4 x = x4[i], t = t4[i];
        float xs[4] = {x.x, x.y, x.z, x.w}, ts[4] = {t.x, t.y, t.z, t.w};
        #pragma unroll
        for (int k = 0; k < 4; k++)
            s += fmaxf(xs[k], 0.0f) - xs[k]*ts[k] + log1pf(expf(-fabsf(xs[k])));
    }
    float tot = blockReduceSum256(s);
    if (threadIdx.x == 0) atomicAdd(&acc[8*ACC_STRIDE], tot);
}

// ---------------- Kernel 3a: per-(b,t) argmax over L=200 (first-index ties) ----------------
__global__ __launch_bounds__(256) void k_argmax(const float* __restrict__ att,
                                                float* __restrict__ peaks) {
    int gwid = (blockIdx.x*256 + threadIdx.x) >> 6;
    int lane = threadIdx.x & 63;
    int nw = (gridDim.x*256) >> 6;
    for (int r = gwid; r < ATT_ROWS; r += nw) {
        const float* rowp = att + (long)r * L_;
        unsigned long long best = 0;
        #pragma unroll
        for (int k = 0; k < 4; k++) {
            int idx = lane + 64*k;
            if (idx < L_) {
                float v = rowp[idx];  // uniform [0,1): positive, int-monotonic bits
                unsigned long long key =
                    ((unsigned long long)__float_as_uint(v) << 32) | (unsigned)(L_-1-idx);
                best = key > best ? key : best;
            }
        }
        #pragma unroll
        for (int off = 32; off; off >>= 1) {
            unsigned long long o = __shfl_down(best, off, 64);
            best = o > best ? o : best;
        }
        if (lane == 0) peaks[r] = (float)(L_ - 1 - (int)(best & 0xffffffffu));
    }
}

// ---------------- Kernel 3b: monotonic violations ----------------
__global__ __launch_bounds__(256) void k_viol(const float* __restrict__ peaks,
                                              float* __restrict__ acc) {
    float s = 0;
    for (int i = blockIdx.x*256 + threadIdx.x; i < ATT_ROWS; i += gridDim.x*256) {
        if (((i + 1) % T_) != 0)
            s += fmaxf(peaks[i] - peaks[i+1], 0.0f);
    }
    float tot = blockReduceSum256(s);
    if (threadIdx.x == 0) atomicAdd(&acc[9*ACC_STRIDE], tot);
}

// ---------------- Kernel 4: Gram partial M = D * S^T (per batch, K-chunked) ----------------
#define GTK  20
#define GPAD 28
__global__ __launch_bounds__(256) void k_gram(const float* __restrict__ mp,
                                              const float* __restrict__ mt,
                                              float* __restrict__ M) {
    const int b  = blockIdx.x >> 2;
    const int ch = blockIdx.x & 3;
    const int k0 = ch * 500;
    __shared__ float Dt[N_MEL][GPAD];
    __shared__ float St[N_MEL][GPAD];
    const int tx = threadIdx.x & 15, ty = threadIdx.x >> 4;
    float m[5][5];
    #pragma unroll
    for (int i = 0; i < 5; i++)
        #pragma unroll
        for (int j = 0; j < 5; j++) m[i][j] = 0;

    const long bbase = (long)b * (N_MEL * T_);
    for (int kt = 0; kt < 25; kt++) {
        int kb = k0 + kt*GTK;
        for (int idx = threadIdx.x; idx < N_MEL*(GTK/4); idx += 256) {
            int c = idx / (GTK/4), q = idx % (GTK/4);
            const float4 p = *(const float4*)(mp + bbase + (long)c*T_ + kb + q*4);
            const float4 t = *(const float4*)(mt + bbase + (long)c*T_ + kb + q*4);
            *(float4*)&Dt[c][q*4] = make_float4(p.x-t.x, p.y-t.y, p.z-t.z, p.w-t.w);
            *(float4*)&St[c][q*4] = make_float4(p.x+t.x, p.y+t.y, p.z+t.z, p.w+t.w);
        }
        __syncthreads();
        #pragma unroll
        for (int q = 0; q < GTK/4; q++) {
            float4 a[5], bb[5];
            #pragma unroll
            for (int i = 0; i < 5; i++) a[i]  = *(const float4*)&Dt[tx + 16*i][q*4];
            #pragma unroll
            for (int j = 0; j < 5; j++) bb[j] = *(const float4*)&St[ty + 16*j][q*4];
            #pragma unroll
            for (int i = 0; i < 5; i++)
                #pragma unroll
                for (int j = 0; j < 5; j++)
                    m[i][j] += a[i].x*bb[j].x + a[i].y*bb[j].y
                             + a[i].z*bb[j].z + a[i].w*bb[j].w;
        }
        __syncthreads();
    }
    #pragma unroll
    for (int i = 0; i < 5; i++)
        #pragma unroll
        for (int j = 0; j < 5; j++)
            atomicAdd(&M[b*6400 + (tx + 16*i)*80 + (ty + 16*j)], m[i][j]);
}

// ---------------- Kernel 5: gram finalize: sum ((M + M^T)/2 / (C*T))^2 ----------------
__global__ __launch_bounds__(256) void k_gramfin(const float* __restrict__ M,
                                                 float* __restrict__ acc) {
    const float inv = 1.0f / (float)(N_MEL * T_);
    float s = 0;
    for (int i = blockIdx.x*256 + threadIdx.x; i < B_*6400; i += gridDim.x*256) {
        int b = i / 6400, cd = i % 6400, c = cd / 80, d = cd % 80;
        float g = 0.5f * (M[i] + M[b*6400 + d*80 + c]) * inv;
        s += g * g;
    }
    float tot = blockReduceSum256(s);
    if (threadIdx.x == 0) atomicAdd(&acc[10*ACC_STRIDE], tot);
}

// ---------------- Kernel 6: combine ----------------
__global__ void k_final(const float* __restrict__ acc, float* __restrict__ out) {
    if (threadIdx.x == 0 && blockIdx.x == 0) {
        const float invN = 1.0f / (float)NTOT;
        float mel        = (acc[0*ACC_STRIDE] + acc[1*ACC_STRIDE]) * invN;
        float gate       = 1.3f * acc[8*ACC_STRIDE] / (float)GATE_N;
        float wmse       = acc[2*ACC_STRIDE] * invN;
        float l1         = acc[3*ACC_STRIDE] * invN;
        float sdiff      = acc[4*ACC_STRIDE] / (float)(B_ * N_MEL * (T_ - 1));
        float spectral   = wmse + 0.3f*l1 + 0.2f*sdiff;
        float perceptual = acc[5*ACC_STRIDE]*invN + 0.5f*l1;
        float mean_loss  = acc[6*ACC_STRIDE] / (float)ROWS;
        float var_loss   = acc[7*ACC_STRIDE] / (float)ROWS;
        float gram       = acc[10*ACC_STRIDE] / (float)(B_ * 6400);
        float style      = mean_loss + var_loss + 0.5f*gram;
        float mono       = acc[9*ACC_STRIDE] / (float)(B_ * T_);
        out[0] = mel + gate + 0.3f*spectral + 0.2f*perceptual + 0.1f*style + 0.1f*mono;
    }
}

extern "C" void kernel_launch(void* const* d_in, const int* in_sizes, int n_in,
                              void* d_out, int out_size, void* d_ws, size_t ws_size,
                              hipStream_t stream) {
    const float* mo  = (const float*)d_in[0];
    const float* mp  = (const float*)d_in[1];
    const float* mt  = (const float*)d_in[2];
    const float* gx  = (const float*)d_in[3];
    const float* gt  = (const float*)d_in[4];
    const float* att = (const float*)d_in[5];
    float* ws      = (float*)d_ws;
    float* acc     = ws;
    float* M       = ws + WS_M;
    float* peaks   = ws + WS_PEAKS;
    float* rowpart = ws + WS_ROWPART;

    // zero accumulators + gram partial buffer; peaks/rowpart fully overwritten
    hipMemsetAsync(d_ws, 0, (size_t)(WS_M + 409600) * sizeof(float), stream);

    k_melrow <<<ROWS, 256, 0, stream>>>(mo, mp, mt, rowpart);
    k_melred <<<20,   256, 0, stream>>>(rowpart, acc);
    k_gate   <<<64,   256, 0, stream>>>(gx, gt, acc);
    k_argmax <<<500,  256, 0, stream>>>(att, peaks);
    k_viol   <<<128,  256, 0, stream>>>(peaks, acc);
    k_gram   <<<256,  256, 0, stream>>>(mp, mt, M);
    k_gramfin<<<128,  256, 0, stream>>>(M, acc);
    k_final  <<<1,    64,  0, stream>>>(acc, (float*)d_out);
}